// Round 15
// baseline (570.713 us; speedup 1.0000x reference)
//
#include <hip/hip_runtime.h>
#include <hip/hip_bf16.h>
#include <math.h>

// ---------------- model constants ----------------
#define BB   64
#define TT   448
#define TTT  449
#define DIM  256
#define HEADS 8
#define HD   32
#define LAYERS 4
#define FFD  1024
#define INDIM 64
#define MPAD 28800
// dependency cone (window [qb-32, qb+47], chunk-granular):
#define TFRONT 160            // front-end rows/batch
#define MFRONT (BB*TFRONT)    // 10240
#define GROWS  168            // guarded rows/batch in h448g (8 zero + 160)

typedef __attribute__((ext_vector_type(8))) short short8;
typedef __attribute__((ext_vector_type(4))) float f32x4;
typedef unsigned short ushort_t;

__device__ __forceinline__ float gelu_f(float x) {
    float x2 = x * x;
    float m = 0.10295219f * x2 + 2.3022635f;
    float t = exp2f(-x * m);
    return x * (1.f / (1.f + t));
}
__device__ __forceinline__ ushort_t f2bf(float x) {
    unsigned u; __builtin_memcpy(&u, &x, 4);
    return (ushort_t)((u + 0x8000u) >> 16);
}
__device__ __forceinline__ unsigned pack2bf(float a, float b) {
    unsigned ua, ub;
    __builtin_memcpy(&ua, &a, 4); __builtin_memcpy(&ub, &b, 4);
    return ((ua + 0x8000u) >> 16) | ((ub + 0x8000u) & 0xffff0000u);
}
__device__ __forceinline__ float bf2f(ushort_t u) {
    unsigned v = ((unsigned)u) << 16; float f; __builtin_memcpy(&f, &v, 4); return f;
}
__device__ __forceinline__ void gload16(const ushort_t* g, ushort_t* l) {
    __builtin_amdgcn_global_load_lds(
        (const __attribute__((address_space(1))) void*)g,
        (__attribute__((address_space(3))) void*)l, 16, 0, 0);
}

// ---------------- bf16 MFMA GEMM (128x128 tile) ----------------
// C[m,n] = sum_k A[m,k] * Bt[n,k]
// a_dil > 0 : conv mode — A is guard-padded h448g [b*168 + 8 + t], t=gm%160.
// a_dil == -1: merged conv (blockIdx.z selects scale s: a_dil=1<<s).
// a_dil == -2: A is f32 x [b*448 + t] (t=gm%160); C2 written to h448g layout.
__global__ __launch_bounds__(256, 3) void gemm_bf16(
    const ushort_t* __restrict__ A, const ushort_t* __restrict__ Bt,
    void* __restrict__ C, ushort_t* __restrict__ C2,
    const float* __restrict__ bias,
    const float* __restrict__ scalev, const float* __restrict__ shiftv,
    int M, int N, int K, int a_dil, int do_gelu, int out_mode)
{
    __shared__ ushort_t smem[2 * 128 * 64];
    ushort_t* As = smem;
    ushort_t* Bs = smem + 128 * 64;
    const int tid = threadIdx.x;
    const int lane = tid & 63, w = tid >> 6;
    const int wm = w >> 1, wn = w & 1;
    const int l15 = lane & 15, quad = lane >> 4;
    const int m0 = blockIdx.y * 128, n0 = blockIdx.x * 128;
    const int sr = lane >> 3, ss = lane & 7;
    const int gsw = ss ^ sr;

    if (a_dil == -1) {                 // merged conv dispatch
        int z = blockIdx.z;
        a_dil = 1 << z;
        Bt += (size_t)z * 196608;
        C = (void*)((ushort_t*)C + (size_t)z * MFRONT * 256);
        bias += z * 256; scalev += z * 256; shiftv += z * 256;
    }
    const ushort_t* aconv[4];
    if (a_dil > 0) {
        #pragma unroll
        for (int j = 0; j < 4; ++j) {
            int r = (w * 4 + j) * 8 + sr;
            int gm = m0 + r;
            int b = gm / TFRONT, t = gm - b * TFRONT;
            aconv[j] = A + ((size_t)(b * GROWS + 8 + t)) * 256 + gsw * 8;
        }
    }
    f32x4 acc[4][4] = {};

    for (int k0 = 0; k0 < K; k0 += 64) {
        if (a_dil > 0) {
            int tap = k0 >> 8;
            int aoff = (k0 & 255) - ((2 - tap) * a_dil) * 256;
            #pragma unroll
            for (int j = 0; j < 4; ++j)
                gload16(aconv[j] + aoff, &As[(w * 4 + j) * 512]);
        } else if (a_dil == -2) {
            const float* Af = (const float*)A;
            #pragma unroll
            for (int j = 0; j < 4; ++j) {
                int r = (w * 4 + j) * 8 + sr;
                int gm = m0 + r;
                int b = gm / TFRONT, t = gm - b * TFRONT;
                const float* ap = Af + ((size_t)b * 448 + t) * K + k0 + gsw * 8;
                float4 a0 = *(const float4*)ap;
                float4 a1 = *(const float4*)(ap + 4);
                uint2 lo = make_uint2(pack2bf(a0.x, a0.y), pack2bf(a0.z, a0.w));
                uint2 hi = make_uint2(pack2bf(a1.x, a1.y), pack2bf(a1.z, a1.w));
                *(uint2*)&As[r * 64 + ss * 8] = lo;
                *(uint2*)&As[r * 64 + ss * 8 + 4] = hi;
            }
        } else {
            #pragma unroll
            for (int j = 0; j < 4; ++j) {
                int r = (w * 4 + j) * 8 + sr;
                int g = ss ^ (r & 7);
                gload16(&A[(size_t)(m0 + r) * K + k0 + g * 8], &As[(w * 4 + j) * 512]);
            }
        }
        #pragma unroll
        for (int j = 0; j < 4; ++j) {
            int r = (w * 4 + j) * 8 + sr;
            int g = ss ^ (r & 7);
            gload16(&Bt[(size_t)(n0 + r) * K + k0 + g * 8], &Bs[(w * 4 + j) * 512]);
        }
        __syncthreads();
        #pragma unroll
        for (int ks = 0; ks < 2; ++ks) {
            short8 af[4], bfr[4];
            #pragma unroll
            for (int i = 0; i < 4; ++i) {
                int row = wm * 64 + i * 16 + l15;
                af[i] = *(const short8*)&As[row * 64 + (((ks * 4 + quad) ^ (l15 & 7)) * 8)];
            }
            #pragma unroll
            for (int j = 0; j < 4; ++j) {
                int row = wn * 64 + j * 16 + l15;
                bfr[j] = *(const short8*)&Bs[row * 64 + (((ks * 4 + quad) ^ (l15 & 7)) * 8)];
            }
            #pragma unroll
            for (int i = 0; i < 4; ++i)
                #pragma unroll
                for (int j = 0; j < 4; ++j)
                    acc[i][j] = __builtin_amdgcn_mfma_f32_16x16x32_bf16(
                        af[i], bfr[j], acc[i][j], 0, 0, 0);
        }
        __syncthreads();
    }

    // ---- vectorized epilogue via per-wave LDS transpose ----
    float* wreg = (float*)smem + w * 2048;
    const int gn0 = n0 + wn * 64 + l15 * 4;
    float4 bias4 = bias ? *(const float4*)&bias[gn0] : make_float4(0.f, 0.f, 0.f, 0.f);
    float4 scl4, shf4;
    if (scalev) { scl4 = *(const float4*)&scalev[gn0]; shf4 = *(const float4*)&shiftv[gn0]; }
    else        { scl4 = make_float4(1.f, 1.f, 1.f, 1.f); shf4 = make_float4(0.f, 0.f, 0.f, 0.f); }

    #pragma unroll
    for (int ci = 0; ci < 2; ++ci) {
        #pragma unroll
        for (int i2 = 0; i2 < 2; ++i2) {
            int i = ci * 2 + i2;
            #pragma unroll
            for (int j = 0; j < 4; ++j) {
                float* col = &wreg[(i2 * 16 + quad * 4) * 64 + j * 16 + l15];
                #pragma unroll
                for (int r = 0; r < 4; ++r) col[r * 64] = acc[i][j][r];
            }
        }
        #pragma unroll
        for (int rr = 0; rr < 8; ++rr) {
            int rl = rr * 4 + quad;
            float4 v = *(float4*)&wreg[rl * 64 + l15 * 4];
            int gm = m0 + wm * 64 + ci * 32 + rl;
            v.x += bias4.x; v.y += bias4.y; v.z += bias4.z; v.w += bias4.w;
            if (do_gelu) { v.x = gelu_f(v.x); v.y = gelu_f(v.y); v.z = gelu_f(v.z); v.w = gelu_f(v.w); }
            v.x = v.x * scl4.x + shf4.x; v.y = v.y * scl4.y + shf4.y;
            v.z = v.z * scl4.z + shf4.z; v.w = v.w * scl4.w + shf4.w;
            if (out_mode == 1) {
                uint2 pk = make_uint2(pack2bf(v.x, v.y), pack2bf(v.z, v.w));
                *(uint2*)&((ushort_t*)C)[(size_t)gm * N + gn0] = pk;
            } else {
                *(float4*)&((float*)C)[(size_t)gm * N + gn0] = v;
                if (out_mode == 2) {
                    int bi = gm / TFRONT, t = gm - bi * TFRONT;
                    size_t grow = (size_t)(bi * GROWS + 8 + t);
                    uint2 pk = make_uint2(pack2bf(v.x, v.y), pack2bf(v.z, v.w));
                    *(uint2*)&C2[grow * N + gn0] = pk;
                }
            }
        }
    }
}

// ---------------- GEMM + fused row-LN epilogue (64x256 full-row tile) --------
// C f32 at mapped row; Y bf16 compact = LN(C row).
// pe_mode: crow = (gm/160)*449+1+gm%160 (add PE), rrow = gm (h448 compact),
//          Y index = b*160 + 1 + t (guard t<159; slot 0 = LN(cls), from prep).
// else: crow = rrow = (gm/rc_mod)*449 + gm%rc_mod; Y index = gm.
__global__ __launch_bounds__(256, 2) void gemm_ln(
    const ushort_t* __restrict__ A, const ushort_t* __restrict__ Bt,
    float* __restrict__ C, ushort_t* __restrict__ Y,
    const float* __restrict__ bias, const float* __restrict__ R,
    const float* __restrict__ lng, const float* __restrict__ lnb,
    int M, int K, int pe_mode, int rc_mod)
{
    __shared__ ushort_t As[64 * 64];     //  8 KB
    __shared__ ushort_t Bs[256 * 64];    // 32 KB; epilogue reuses as f32 buf
    const int tid = threadIdx.x;
    const int lane = tid & 63, w = tid >> 6;
    const int l15 = lane & 15, quad = lane >> 4;
    const int m0 = blockIdx.x * 64;
    const int sr = lane >> 3, ss = lane & 7;
    f32x4 acc[16] = {};

    for (int k0 = 0; k0 < K; k0 += 64) {
        #pragma unroll
        for (int j = 0; j < 2; ++j) {
            int r = (w * 2 + j) * 8 + sr;
            int g = ss ^ (r & 7);
            gload16(&A[(size_t)(m0 + r) * K + k0 + g * 8], &As[(w * 2 + j) * 512]);
        }
        #pragma unroll
        for (int j = 0; j < 8; ++j) {
            int r = (w * 8 + j) * 8 + sr;
            int g = ss ^ (r & 7);
            gload16(&Bt[(size_t)r * K + k0 + g * 8], &Bs[(w * 8 + j) * 512]);
        }
        __syncthreads();
        #pragma unroll
        for (int ks = 0; ks < 2; ++ks) {
            int arow = w * 16 + l15;
            short8 af = *(const short8*)&As[arow * 64 + (((ks * 4 + quad) ^ (l15 & 7)) * 8)];
            #pragma unroll
            for (int j = 0; j < 16; ++j) {
                int brow = j * 16 + l15;
                short8 bf = *(const short8*)&Bs[brow * 64 + (((ks * 4 + quad) ^ (l15 & 7)) * 8)];
                acc[j] = __builtin_amdgcn_mfma_f32_16x16x32_bf16(af, bf, acc[j], 0, 0, 0);
            }
        }
        __syncthreads();
    }

    // ---- epilogue: per-row bias(+PE)+R -> h449 f32; LN -> Y bf16 ----
    float* epi = (float*)Bs + w * 2048;      // 8 KB per wave
    const int c0 = lane * 4;
    float4 bias4 = *(const float4*)&bias[c0];
    float4 gv = *(const float4*)&lng[c0];
    float4 bv = *(const float4*)&lnb[c0];

    #pragma unroll
    for (int p = 0; p < 2; ++p) {
        int qloc = quad - 2 * p;
        if (qloc >= 0 && qloc < 2) {
            #pragma unroll
            for (int j = 0; j < 16; ++j)
                #pragma unroll
                for (int r = 0; r < 4; ++r)
                    epi[(qloc * 4 + r) * 256 + j * 16 + l15] = acc[j][r];
        }
        for (int r8 = 0; r8 < 8; ++r8) {
            int gm = m0 + w * 16 + p * 8 + r8;
            float4 v = *(float4*)&epi[r8 * 256 + c0];
            v.x += bias4.x; v.y += bias4.y; v.z += bias4.z; v.w += bias4.w;
            size_t crow, rrow, yrow;
            bool ywrite = true;
            if (pe_mode) {
                int bi = gm / TFRONT, t = gm - bi * TFRONT;
                crow = (size_t)bi * 449 + 1 + t;
                rrow = (size_t)gm;
                yrow = (size_t)bi * TFRONT + 1 + t;
                ywrite = (t < TFRONT - 1);
                float ft = (float)t;
                float f0 = __expf(-9.210340371976184f * (float)c0 * (1.f / 256.f));
                float f1 = __expf(-9.210340371976184f * (float)(c0 + 2) * (1.f / 256.f));
                float a0 = ft * f0, a1 = ft * f1;
                v.x += __sinf(a0); v.y += __cosf(a0);
                v.z += __sinf(a1); v.w += __cosf(a1);
            } else {
                crow = (size_t)(gm / rc_mod) * 449 + (gm % rc_mod);
                rrow = crow;
                yrow = (size_t)gm;
            }
            {
                float4 r4 = *(const float4*)&R[rrow * 256 + c0];
                v.x += r4.x; v.y += r4.y; v.z += r4.z; v.w += r4.w;
            }
            *(float4*)&C[crow * 256 + c0] = v;
            float s = v.x + v.y + v.z + v.w;
            #pragma unroll
            for (int o = 32; o > 0; o >>= 1) s += __shfl_xor(s, o);
            float mean = s * (1.f / 256.f);
            float dx = v.x - mean, dy = v.y - mean, dz = v.z - mean, dw = v.w - mean;
            float s2 = dx * dx + dy * dy + dz * dz + dw * dw;
            #pragma unroll
            for (int o = 32; o > 0; o >>= 1) s2 += __shfl_xor(s2, o);
            float rstd = rsqrtf(s2 * (1.f / 256.f) + 1e-5f);
            if (ywrite)
                *(uint2*)&Y[yrow * 256 + c0] = make_uint2(
                    pack2bf(dx * rstd * gv.x + bv.x, dy * rstd * gv.y + bv.y),
                    pack2bf(dz * rstd * gv.z + bv.z, dw * rstd * gv.w + bv.w));
        }
    }
}

// ---- prep: transposes + conv repack + BN + guards + cls copy + cls-LN ------
__global__ __launch_bounds__(256) void prep_all(
    const float* __restrict__ ipw,  const float* __restrict__ mpw,
    const float* __restrict__ qkvw, const float* __restrict__ outw,
    const float* __restrict__ fw1,  const float* __restrict__ fw2,
    const float* __restrict__ cw1,
    ushort_t* ipwT, ushort_t* mpwT, ushort_t* qkvT, ushort_t* outwT,
    ushort_t* fw1T, ushort_t* fw2T, ushort_t* cw1T,
    const float* __restrict__ convw, ushort_t* wrepT,
    const float* __restrict__ bg, const float* __restrict__ bb,
    const float* __restrict__ rm, const float* __restrict__ rv,
    float* bnsc, float* bnsh,
    ushort_t* h448g, const float* __restrict__ clstok, float* h449,
    const float* __restrict__ ln1g, const float* __restrict__ ln1b,
    ushort_t* bufB2)
{
    const int bid = blockIdx.x;
    __shared__ float red[4];
    if (bid >= 3239) {                        // LN1_0(clstok) -> bufB2 cls slots
        int d = threadIdx.x, w = d >> 6, lane = d & 63;
        float v = clstok[d];
        float s = v;
        #pragma unroll
        for (int o = 32; o > 0; o >>= 1) s += __shfl_xor(s, o);
        if (lane == 0) red[w] = s;
        __syncthreads();
        float mean = (red[0] + red[1] + red[2] + red[3]) * (1.f / 256.f);
        __syncthreads();
        float diff = v - mean;
        float s2 = diff * diff;
        #pragma unroll
        for (int o = 32; o > 0; o >>= 1) s2 += __shfl_xor(s2, o);
        if (lane == 0) red[w] = s2;
        __syncthreads();
        float rstd = rsqrtf((red[0] + red[1] + red[2] + red[3]) * (1.f / 256.f) + 1e-5f);
        ushort_t q = f2bf(diff * rstd * ln1g[d] + ln1b[d]);
        for (int b = 0; b < BB; ++b)
            bufB2[(size_t)(b * TFRONT) * 256 + d] = q;
        return;
    }
    if (bid >= 3175) {                        // cls-token copy into h449 row 0
        int b = bid - 3175;
        h449[(size_t)b * TTT * 256 + threadIdx.x] = clstok[threadIdx.x];
        return;
    }
    if (bid >= 3111) {                        // zero guard rows of h448g
        int b = bid - 3111;
        #pragma unroll
        for (int j = 0; j < 8; ++j)
            h448g[(size_t)(b * GROWS + j) * 256 + threadIdx.x] = 0;
        return;
    }
    if (bid >= 3108) {                        // BN folding
        int i = (bid - 3108) * 256 + threadIdx.x;
        if (i < 768) {
            float sc = rsqrtf(rv[i] + 1e-5f) * bg[i];
            bnsc[i] = sc;
            bnsh[i] = bb[i] - rm[i] * sc;
        }
        return;
    }
    if (bid >= 804) {                         // conv weight repack
        int i = (bid - 804) * 256 + threadIdx.x;
        int s = i / 196608; int o = i - s * 196608;
        int ci = o & 255; int t3 = (o >> 8) % 3; int co = o / 768;
        wrepT[i] = f2bf(convw[(((size_t)s * 256 + co) * 256 + ci) * 3 + t3]);
        return;
    }
    const float* src; ushort_t* dst; int K, N, local;
    if (bid < 4)        { src = ipw;  dst = ipwT;  K = 64;   N = 256;  local = bid; }
    else if (bid < 20)  { src = mpw;  dst = mpwT;  K = 256;  N = 256;  local = bid - 4; }
    else if (bid < 212) { int l = bid - 20;  int z = l / 48; l -= z * 48;
                          src = qkvw + (size_t)z * 196608; dst = qkvT + (size_t)z * 196608;
                          K = 256;  N = 768;  local = l; }
    else if (bid < 276) { int l = bid - 212; int z = l / 16; l -= z * 16;
                          src = outw + (size_t)z * 65536;  dst = outwT + (size_t)z * 65536;
                          K = 256;  N = 256;  local = l; }
    else if (bid < 532) { int l = bid - 276; int z = l / 64; l -= z * 64;
                          src = fw1 + (size_t)z * 262144;  dst = fw1T + (size_t)z * 262144;
                          K = 256;  N = 1024; local = l; }
    else if (bid < 788) { int l = bid - 532; int z = l / 64; l -= z * 64;
                          src = fw2 + (size_t)z * 262144;  dst = fw2T + (size_t)z * 262144;
                          K = 1024; N = 256;  local = l; }
    else                { src = cw1;  dst = cw1T;  K = 256;  N = 256;  local = bid - 788; }

    __shared__ float tile[64][65];
    int nt = N / 64;
    int n0 = (local % nt) * 64, k0 = (local / nt) * 64;
    int tx = threadIdx.x & 63, ty = threadIdx.x >> 6;
    #pragma unroll
    for (int i = 0; i < 16; ++i)
        tile[i * 4 + ty][tx] = src[(size_t)(k0 + i * 4 + ty) * N + n0 + tx];
    __syncthreads();
    #pragma unroll
    for (int i = 0; i < 16; ++i) {
        int n = i * 4 + ty;
        dst[(size_t)(n0 + n) * K + k0 + tx] = f2bf(tile[tx][n]);
    }
}

// ---------------- gate softmax + fuse, wave-per-row ----------------
__global__ __launch_bounds__(256) void gate_fuse(
    const ushort_t* __restrict__ conv,  // [3][Mrows][256]
    const float* __restrict__ gw, const float* __restrict__ gb,
    ushort_t* __restrict__ fused, int Mrows)
{
    const int w = threadIdx.x >> 6, lane = threadIdx.x & 63;
    const int m = blockIdx.x * 4 + w;
    const int d0 = lane * 4;
    float vals[3][4];
    float p0 = 0.f, p1 = 0.f, p2 = 0.f;
    #pragma unroll
    for (int s = 0; s < 3; ++s) {
        uint2 pk = *(const uint2*)&conv[((size_t)s * Mrows + m) * 256 + d0];
        vals[s][0] = bf2f(pk.x & 0xffff); vals[s][1] = bf2f(pk.x >> 16);
        vals[s][2] = bf2f(pk.y & 0xffff); vals[s][3] = bf2f(pk.y >> 16);
        #pragma unroll
        for (int e = 0; e < 4; ++e) {
            const float* wp = gw + (size_t)(s * 256 + d0 + e) * 3;
            float v = vals[s][e];
            p0 += v * wp[0]; p1 += v * wp[1]; p2 += v * wp[2];
        }
    }
    #pragma unroll
    for (int o = 32; o > 0; o >>= 1) {
        p0 += __shfl_xor(p0, o); p1 += __shfl_xor(p1, o); p2 += __shfl_xor(p2, o);
    }
    float l0 = p0 + gb[0], l1 = p1 + gb[1], l2 = p2 + gb[2];
    float mx = fmaxf(l0, fmaxf(l1, l2));
    float e0 = __expf(l0 - mx), e1 = __expf(l1 - mx), e2 = __expf(l2 - mx);
    float inv = 1.f / (e0 + e1 + e2);
    float g0 = e0 * inv, g1 = e1 * inv, g2 = e2 * inv;
    unsigned r0 = pack2bf(vals[0][0] * g0 + vals[1][0] * g1 + vals[2][0] * g2,
                          vals[0][1] * g0 + vals[1][1] * g1 + vals[2][1] * g2);
    unsigned r1 = pack2bf(vals[0][2] * g0 + vals[1][2] * g1 + vals[2][2] * g2,
                          vals[0][3] * g0 + vals[1][3] * g1 + vals[2][3] * g2);
    *(uint2*)&fused[(size_t)m * 256 + d0] = make_uint2(r0, r1);
}

// ---------------- attention v8b: compact strides, window [qb-32, qb+47] ------
#define KP    480
#define KPAD  36
#define VPAD  488
#define PTPAD 40
__global__ __launch_bounds__(256, 2) void attn8_kernel(
    const ushort_t* __restrict__ qkv,
    const float* __restrict__ alpha,
    ushort_t* __restrict__ O,
    int kst, int nqt, int ost)
{
    __shared__ ushort_t sK[KP][KPAD];
    __shared__ ushort_t sVt[32][VPAD];
    __shared__ ushort_t sPT[4][16][PTPAD];
    __shared__ float sRed[4];

    const int bh = blockIdx.x;
    const int b = bh >> 3, h = bh & 7;
    const int tid = threadIdx.x;
    const int w = tid >> 6, lane = tid & 63;
    const int l15 = lane & 15, quad = lane >> 4;
    const float LOG2E = 1.4426950408889634f;
    const float scale2 = 0.17677669529663687f * LOG2E;

    float av = alpha[h];
    float a_sp = (av > 20.f) ? av : log1pf(__expf(av));
    const float a_h = a_sp * LOG2E;

    {
        int r0 = tid >> 2, c = (tid & 3) * 8;
        float knmax = 0.f;
        for (int r = r0; r < kst; r += 64) {
            const ushort_t* src = qkv + ((size_t)(b * kst + r)) * 768 + 256 + h * 32 + c;
            short8 kv = *(const short8*)src;
            short8 vv = *(const short8*)(src + 256);
            *(short8*)&sK[r][c] = kv;
            float ssq = 0.f;
            #pragma unroll
            for (int j = 0; j < 8; ++j) {
                float kf = bf2f(((const ushort_t*)&kv)[j]);
                ssq += kf * kf;
                sVt[c + j][r] = ((const ushort_t*)&vv)[j];
            }
            ssq += __shfl_xor(ssq, 1);
            ssq += __shfl_xor(ssq, 2);
            knmax = fmaxf(knmax, ssq);
        }
        #pragma unroll
        for (int o = 32; o > 0; o >>= 1) knmax = fmaxf(knmax, __shfl_xor(knmax, o));
        if (lane == 0) sRed[w] = knmax;
    }
    __syncthreads();
    const float kmax2 = fmaxf(fmaxf(sRed[0], sRed[1]), fmaxf(sRed[2], sRed[3]));

    for (int qt = w; qt < nqt; qt += 4) {
        const int qb = qt * 16;
        const int qrow = qb + l15;
        short8 qfrag = *(const short8*)(qkv + ((size_t)(b * kst + qrow)) * 768 + h * 32 + quad * 8);
        const f32x4 z = {0.f, 0.f, 0.f, 0.f};

        float qn = 0.f;
        #pragma unroll
        for (int j = 0; j < 8; ++j) { float f = bf2f(qfrag[j]); qn += f * f; }
        qn += __shfl_xor(qn, 16);
        qn += __shfl_xor(qn, 32);
        const float Mr = scale2 * sqrtf(qn * kmax2);
        const float fq = (float)qrow;

        int ch_lo = (qb - 32) >> 5; if (ch_lo < 0) ch_lo = 0;
        int ch_hi = (qb + 47) >> 5;
        const int ch_max = (kst >> 5) - 1;
        if (ch_hi > ch_max) ch_hi = ch_max;

        f32x4 o0 = z, o1 = z;
        float lsum = 0.f;
        for (int ch = ch_lo; ch <= ch_hi; ++ch) {
            const int kb = ch * 32;
            short8 kf0 = *(const short8*)&sK[kb + l15][quad * 8];
            short8 kf1 = *(const short8*)&sK[kb + 16 + l15][quad * 8];
            f32x4 s0 = __builtin_amdgcn_mfma_f32_16x16x32_bf16(kf0, qfrag, z, 0, 0, 0);
            f32x4 s1 = __builtin_amdgcn_mfma_f32_16x16x32_bf16(kf1, qfrag, z, 0, 0, 0);
            float p0[4], p1[4];
            #pragma unroll
            for (int r = 0; r < 4; ++r) {
                int k0 = kb + quad * 4 + r;
                int k1 = k0 + 16;
                float b0 = s0[r] * scale2 - (a_h * fabsf(fq - (float)k0) + Mr);
                float b1 = s1[r] * scale2 - (a_h * fabsf(fq - (float)k1) + Mr);
                p0[r] = exp2f(b0);
                p1[r] = exp2f(b1);
            }
            lsum += (p0[0] + p0[1]) + (p0[2] + p0[3]) + (p1[0] + p1[1]) + (p1[2] + p1[3]);
            unsigned* prow = (unsigned*)&sPT[w][l15][0];
            prow[quad * 2]     = pack2bf(p0[0], p0[1]);
            prow[quad * 2 + 1] = pack2bf(p0[2], p0[3]);
            prow[8 + quad * 2]     = pack2bf(p1[0], p1[1]);
            prow[8 + quad * 2 + 1] = pack2bf(p1[2], p1[3]);
            short8 pB = *(const short8*)&sPT[w][l15][quad * 8];
            short8 v0 = *(const short8*)&sVt[l15][kb + quad * 8];
            short8 v1 = *(const short8*)&sVt[16 + l15][kb + quad * 8];
            o0 = __builtin_amdgcn_mfma_f32_16x16x32_bf16(v0, pB, o0, 0, 0, 0);
            o1 = __builtin_amdgcn_mfma_f32_16x16x32_bf16(v1, pB, o1, 0, 0, 0);
        }
        lsum += __shfl_xor(lsum, 16);
        lsum += __shfl_xor(lsum, 32);

        {
            float inv = 1.f / lsum;
            unsigned* dst = (unsigned*)&O[((size_t)(b * ost + qrow)) * 256 + h * 32 + quad * 4];
            dst[0] = pack2bf(o0[0] * inv, o0[1] * inv);
            dst[1] = pack2bf(o0[2] * inv, o0[3] * inv);
            dst[8] = pack2bf(o1[0] * inv, o1[1] * inv);
            dst[9] = pack2bf(o1[2] * inv, o1[3] * inv);
        }
    }
}

// ---------------- head: cls MLP + logit (LN already fused into ffn2 l3) ------
__global__ __launch_bounds__(256) void head_kernel(
    const ushort_t* __restrict__ Yln,   // compact [b*16 + q][256], q=0 is cls
    const ushort_t* __restrict__ cw1T, const float* __restrict__ cb1,
    const float* __restrict__ cw2, const float* __restrict__ b2,
    float* __restrict__ out)
{
    __shared__ float xn[256];
    __shared__ float red[4];
    const int b = blockIdx.x, d = threadIdx.x;
    xn[d] = bf2f(Yln[((size_t)b * 16) * 256 + d]);
    __syncthreads();
    const ushort_t* wrow = cw1T + (size_t)d * 256;
    float acc = 0.f;
    #pragma unroll 4
    for (int k = 0; k < 256; k += 8) {
        short8 wv = *(const short8*)&wrow[k];
        #pragma unroll
        for (int j = 0; j < 8; ++j) acc += xn[k + j] * bf2f(((const ushort_t*)&wv)[j]);
    }
    float p = gelu_f(acc + cb1[d]) * cw2[d];
    #pragma unroll
    for (int o = 32; o > 0; o >>= 1) p += __shfl_down(p, o, 64);
    if ((d & 63) == 0) red[d >> 6] = p;
    __syncthreads();
    if (d == 0) out[b] = red[0] + red[1] + red[2] + red[3] + b2[0];
}

// ---------------- orchestration ----------------
extern "C" void kernel_launch(void* const* d_in, const int* in_sizes, int n_in,
                              void* d_out, int out_size, void* d_ws, size_t ws_size,
                              hipStream_t stream)
{
    const float* x      = (const float*)d_in[0];
    const float* ipw    = (const float*)d_in[1];
    const float* ipb    = (const float*)d_in[2];
    const float* convw  = (const float*)d_in[3];
    const float* convb  = (const float*)d_in[4];
    const float* bng    = (const float*)d_in[5];
    const float* bnb    = (const float*)d_in[6];
    const float* bnrm   = (const float*)d_in[7];
    const float* bnrv   = (const float*)d_in[8];
    const float* gatew  = (const float*)d_in[9];
    const float* gateb  = (const float*)d_in[10];
    const float* mpw    = (const float*)d_in[11];
    const float* mpb    = (const float*)d_in[12];
    const float* clstok = (const float*)d_in[13];
    const float* qkvw   = (const float*)d_in[14];
    const float* qkvb   = (const float*)d_in[15];
    const float* outw   = (const float*)d_in[16];
    const float* outb   = (const float*)d_in[17];
    const float* alpha  = (const float*)d_in[18];
    const float* ln1g   = (const float*)d_in[19];
    const float* ln1b   = (const float*)d_in[20];
    const float* ln2g   = (const float*)d_in[21];
    const float* ln2b   = (const float*)d_in[22];
    const float* fw1    = (const float*)d_in[23];
    const float* fb1    = (const float*)d_in[24];
    const float* fw2    = (const float*)d_in[25];
    const float* fb2    = (const float*)d_in[26];
    const float* fing   = (const float*)d_in[27];
    const float* finb   = (const float*)d_in[28];
    const float* cw1    = (const float*)d_in[29];
    const float* cb1    = (const float*)d_in[30];
    const float* cw2    = (const float*)d_in[31];
    const float* cb2    = (const float*)d_in[32];

    const int KL[4] = {160, 128, 96, 64};
    const int QL[4] = {128, 96, 64, 16};

    // ---- workspace layout ----
    char* base = (char*)d_ws;
    size_t off = 0;
    auto alloc = [&](size_t bytes) { char* p = base + off; off += (bytes + 255) & ~(size_t)255; return p; };
    float*    h448  = (float*)alloc((size_t)MFRONT * 256 * 4);
    float*    h449  = (float*)alloc((size_t)MPAD * 256 * 4);
    float*    bufA  = (float*)alloc((size_t)MFRONT * 768 * 4);
    ushort_t* conv_bf = (ushort_t*)bufA;
    ushort_t* qkv_bf  = (ushort_t*)bufA;
    ushort_t* bufMid  = (ushort_t*)bufA;
    ushort_t* bufB  = (ushort_t*)alloc((size_t)MFRONT * 256 * 2);   // gate out
    ushort_t* bufB2 = (ushort_t*)alloc((size_t)MFRONT * 256 * 2);   // LN outputs
    ushort_t* bufC  = (ushort_t*)alloc((size_t)64 * 128 * 256 * 2);
    ushort_t* h448g = (ushort_t*)alloc((size_t)BB * GROWS * 256 * 2);
    ushort_t* wrepT = (ushort_t*)alloc((size_t)3 * 256 * 768 * 2);
    ushort_t* ipwT  = (ushort_t*)alloc((size_t)64 * 256 * 2);
    ushort_t* mpwT  = (ushort_t*)alloc((size_t)256 * 256 * 2);
    ushort_t* qkvT  = (ushort_t*)alloc((size_t)4 * 768 * 256 * 2);
    ushort_t* outwT = (ushort_t*)alloc((size_t)4 * 256 * 256 * 2);
    ushort_t* fw1T  = (ushort_t*)alloc((size_t)4 * 1024 * 256 * 2);
    ushort_t* fw2T  = (ushort_t*)alloc((size_t)4 * 256 * 1024 * 2);
    ushort_t* cw1T  = (ushort_t*)alloc((size_t)256 * 256 * 2);
    float*    bnsc  = (float*)alloc(768 * 4);
    float*    bnsh  = (float*)alloc(768 * 4);

    auto gemm = [&](const ushort_t* A, const ushort_t* Bt, void* C, ushort_t* C2,
                    const float* bias, const float* scl, const float* shf,
                    int M, int N, int K, int a_dil, int gelu_fl, int omode, int gz = 1) {
        dim3 grid(N / 128, M / 128, gz);
        hipLaunchKernelGGL(gemm_bf16, grid, dim3(256), 0, stream,
                           A, Bt, C, C2, bias, scl, shf, M, N, K, a_dil, gelu_fl, omode);
    };
    auto gemmln = [&](const ushort_t* A, const ushort_t* Bt, ushort_t* Y,
                      const float* bias, const float* R,
                      const float* lg, const float* lb,
                      int M, int K, int pe, int rc) {
        hipLaunchKernelGGL(gemm_ln, dim3(M / 64), dim3(256), 0, stream,
                           A, Bt, h449, Y, bias, R, lg, lb, M, K, pe, rc);
    };

    // ---- prep ----
    hipLaunchKernelGGL(prep_all, dim3(3240), dim3(256), 0, stream,
                       ipw, mpw, qkvw, outw, fw1, fw2, cw1,
                       ipwT, mpwT, qkvT, outwT, fw1T, fw2T, cw1T,
                       convw, wrepT, bng, bnb, bnrm, bnrv, bnsc, bnsh,
                       h448g, clstok, h449, ln1g, ln1b, bufB2);

    // ---- input projection: h448 f32 + h448g bf16 (guarded) ----
    gemm((const ushort_t*)x, ipwT, h448, h448g, ipb, nullptr, nullptr,
         MFRONT, 256, 64, -2, 0, 2);

    // ---- conv (3 scales in z), DMA staging from h448g, fused gelu+BN ----
    gemm(h448g, wrepT, conv_bf, nullptr, convb, bnsc, bnsh,
         MFRONT, 256, 768, -1, 1, 1, 3);
    hipLaunchKernelGGL(gate_fuse, dim3(MFRONT / 4), dim3(256), 0, stream,
                       conv_bf, gatew, gateb, bufB, MFRONT);
    // ms_proj + residual(h448) + PE -> h449; fused ln1(l0) -> bufB2 (shifted +1)
    gemmln(bufB, mpwT, bufB2, mpb, h448, ln1g, ln1b, MFRONT, 256, 1, 0);

    // ---- transformer layers ----
    for (int l = 0; l < LAYERS; ++l) {
        const int Kl = KL[l], Ql = QL[l];
        const int MK = 64 * Kl, MQ = 64 * Ql;
        gemm(bufB2, qkvT + (size_t)l * 768 * 256, qkv_bf, nullptr, qkvb + l * 768,
             nullptr, nullptr, MK, 768, 256, 0, 0, 1);
        hipLaunchKernelGGL(attn8_kernel, dim3(BB * HEADS), dim3(256), 0, stream,
                           qkv_bf, alpha + l * HEADS, bufC, Kl, Ql / 16, Ql);
        // out-proj + residual(h449) -> h449; fused ln2 -> bufB2
        gemmln(bufC, outwT + (size_t)l * 65536, bufB2, outb + l * 256, h449,
               ln2g + l * 256, ln2b + l * 256, MQ, 256, 0, Ql);
        gemm(bufB2, fw1T + (size_t)l * 262144, bufMid, nullptr, fb1 + l * 1024,
             nullptr, nullptr, MQ, 1024, 256, 0, 1, 1);
        // ffn2 + residual -> h449; fused LN -> bufB2 (next ln1, or final LN at l=3)
        const float* lg = (l < LAYERS - 1) ? ln1g + (l + 1) * 256 : fing;
        const float* lb = (l < LAYERS - 1) ? ln1b + (l + 1) * 256 : finb;
        gemmln(bufMid, fw2T + (size_t)l * 262144, bufB2, fb2 + l * 256, h449,
               lg, lb, MQ, 1024, 0, Ql);
    }

    // ---- head: cls MLP + logit (final LN already applied in ffn2 l3) ----
    hipLaunchKernelGGL(head_kernel, dim3(BB), dim3(256), 0, stream,
                       bufB2, cw1T, cb1, cw2, cb2, (float*)d_out);
}

// Round 16
// 533.031 us; speedup vs baseline: 1.0707x; 1.0707x over previous
//
#include <hip/hip_runtime.h>
#include <hip/hip_bf16.h>
#include <math.h>

// ---------------- model constants ----------------
#define BB   64
#define TT   448
#define TTT  449
#define DIM  256
#define HEADS 8
#define HD   32
#define LAYERS 4
#define FFD  1024
#define INDIM 64
#define MPAD 28800
// dependency cone (window [qb-32, qb+47], chunk-granular):
#define TFRONT 160            // front-end rows/batch
#define MFRONT (BB*TFRONT)    // 10240
#define GROWS  168            // guarded rows/batch in h448g (8 zero + 160)

typedef __attribute__((ext_vector_type(8))) short short8;
typedef __attribute__((ext_vector_type(4))) float f32x4;
typedef unsigned short ushort_t;

__device__ __forceinline__ float gelu_f(float x) {
    float x2 = x * x;
    float m = 0.10295219f * x2 + 2.3022635f;
    float t = exp2f(-x * m);
    return x * (1.f / (1.f + t));
}
__device__ __forceinline__ ushort_t f2bf(float x) {
    unsigned u; __builtin_memcpy(&u, &x, 4);
    return (ushort_t)((u + 0x8000u) >> 16);
}
__device__ __forceinline__ unsigned pack2bf(float a, float b) {
    unsigned ua, ub;
    __builtin_memcpy(&ua, &a, 4); __builtin_memcpy(&ub, &b, 4);
    return ((ua + 0x8000u) >> 16) | ((ub + 0x8000u) & 0xffff0000u);
}
__device__ __forceinline__ float bf2f(ushort_t u) {
    unsigned v = ((unsigned)u) << 16; float f; __builtin_memcpy(&f, &v, 4); return f;
}
__device__ __forceinline__ void gload16(const ushort_t* g, ushort_t* l) {
    __builtin_amdgcn_global_load_lds(
        (const __attribute__((address_space(1))) void*)g,
        (__attribute__((address_space(3))) void*)l, 16, 0, 0);
}

// ---------------- bf16 MFMA GEMM v7 (R12 structure) ----------------
// C[m,n] = sum_k A[m,k] * Bt[n,k]
// a_dil > 0 : conv mode — A is guard-padded h448g [b*168 + 8 + t], t=gm%160.
// a_dil == -1: merged conv (blockIdx.z selects scale s: a_dil=1<<s).
// a_dil == -2: A is f32 x [b*448 + t] (t=gm%160); C2 written to h448g layout.
// rc_mod > 0: R and C row = (gm/rc_mod)*449 + gm%rc_mod (h449 layout).
// pe_mode: C row = (gm/160)*449 + 1 + gm%160, add sinusoidal PE (f32 out).
__global__ __launch_bounds__(256, 3) void gemm_bf16(
    const ushort_t* __restrict__ A, const ushort_t* __restrict__ Bt,
    void* __restrict__ C, ushort_t* __restrict__ C2,
    const float* __restrict__ bias,
    const float* __restrict__ scalev, const float* __restrict__ shiftv,
    const float* __restrict__ R,
    int M, int N, int K, int a_dil, int do_gelu, int out_mode, int pe_mode,
    int rc_mod)
{
    __shared__ ushort_t smem[2 * 128 * 64];
    ushort_t* As = smem;
    ushort_t* Bs = smem + 128 * 64;
    const int tid = threadIdx.x;
    const int lane = tid & 63, w = tid >> 6;
    const int wm = w >> 1, wn = w & 1;
    const int l15 = lane & 15, quad = lane >> 4;
    const int m0 = blockIdx.y * 128, n0 = blockIdx.x * 128;
    const int sr = lane >> 3, ss = lane & 7;
    const int gsw = ss ^ sr;

    if (a_dil == -1) {                 // merged conv dispatch
        int z = blockIdx.z;
        a_dil = 1 << z;
        Bt += (size_t)z * 196608;
        C = (void*)((ushort_t*)C + (size_t)z * MFRONT * 256);
        bias += z * 256; scalev += z * 256; shiftv += z * 256;
    }
    const ushort_t* aconv[4];
    if (a_dil > 0) {
        #pragma unroll
        for (int j = 0; j < 4; ++j) {
            int r = (w * 4 + j) * 8 + sr;
            int gm = m0 + r;
            int b = gm / TFRONT, t = gm - b * TFRONT;
            aconv[j] = A + ((size_t)(b * GROWS + 8 + t)) * 256 + gsw * 8;
        }
    }
    f32x4 acc[4][4] = {};

    for (int k0 = 0; k0 < K; k0 += 64) {
        if (a_dil > 0) {
            int tap = k0 >> 8;
            int aoff = (k0 & 255) - ((2 - tap) * a_dil) * 256;
            #pragma unroll
            for (int j = 0; j < 4; ++j)
                gload16(aconv[j] + aoff, &As[(w * 4 + j) * 512]);
        } else if (a_dil == -2) {
            const float* Af = (const float*)A;
            #pragma unroll
            for (int j = 0; j < 4; ++j) {
                int r = (w * 4 + j) * 8 + sr;
                int gm = m0 + r;
                int b = gm / TFRONT, t = gm - b * TFRONT;
                const float* ap = Af + ((size_t)b * 448 + t) * K + k0 + gsw * 8;
                float4 a0 = *(const float4*)ap;
                float4 a1 = *(const float4*)(ap + 4);
                uint2 lo = make_uint2(pack2bf(a0.x, a0.y), pack2bf(a0.z, a0.w));
                uint2 hi = make_uint2(pack2bf(a1.x, a1.y), pack2bf(a1.z, a1.w));
                *(uint2*)&As[r * 64 + ss * 8] = lo;
                *(uint2*)&As[r * 64 + ss * 8 + 4] = hi;
            }
        } else {
            #pragma unroll
            for (int j = 0; j < 4; ++j) {
                int r = (w * 4 + j) * 8 + sr;
                int g = ss ^ (r & 7);
                gload16(&A[(size_t)(m0 + r) * K + k0 + g * 8], &As[(w * 4 + j) * 512]);
            }
        }
        #pragma unroll
        for (int j = 0; j < 4; ++j) {
            int r = (w * 4 + j) * 8 + sr;
            int g = ss ^ (r & 7);
            gload16(&Bt[(size_t)(n0 + r) * K + k0 + g * 8], &Bs[(w * 4 + j) * 512]);
        }
        __syncthreads();
        #pragma unroll
        for (int ks = 0; ks < 2; ++ks) {
            short8 af[4], bfr[4];
            #pragma unroll
            for (int i = 0; i < 4; ++i) {
                int row = wm * 64 + i * 16 + l15;
                af[i] = *(const short8*)&As[row * 64 + (((ks * 4 + quad) ^ (l15 & 7)) * 8)];
            }
            #pragma unroll
            for (int j = 0; j < 4; ++j) {
                int row = wn * 64 + j * 16 + l15;
                bfr[j] = *(const short8*)&Bs[row * 64 + (((ks * 4 + quad) ^ (l15 & 7)) * 8)];
            }
            #pragma unroll
            for (int i = 0; i < 4; ++i)
                #pragma unroll
                for (int j = 0; j < 4; ++j)
                    acc[i][j] = __builtin_amdgcn_mfma_f32_16x16x32_bf16(
                        af[i], bfr[j], acc[i][j], 0, 0, 0);
        }
        __syncthreads();
    }

    // ---- vectorized epilogue via per-wave LDS transpose ----
    float* wreg = (float*)smem + w * 2048;
    const int gn0 = n0 + wn * 64 + l15 * 4;
    float4 bias4 = bias ? *(const float4*)&bias[gn0] : make_float4(0.f, 0.f, 0.f, 0.f);
    float4 scl4, shf4;
    if (scalev) { scl4 = *(const float4*)&scalev[gn0]; shf4 = *(const float4*)&shiftv[gn0]; }
    else        { scl4 = make_float4(1.f, 1.f, 1.f, 1.f); shf4 = make_float4(0.f, 0.f, 0.f, 0.f); }

    #pragma unroll
    for (int ci = 0; ci < 2; ++ci) {
        #pragma unroll
        for (int i2 = 0; i2 < 2; ++i2) {
            int i = ci * 2 + i2;
            #pragma unroll
            for (int j = 0; j < 4; ++j) {
                float* col = &wreg[(i2 * 16 + quad * 4) * 64 + j * 16 + l15];
                #pragma unroll
                for (int r = 0; r < 4; ++r) col[r * 64] = acc[i][j][r];
            }
        }
        #pragma unroll
        for (int rr = 0; rr < 8; ++rr) {
            int rl = rr * 4 + quad;
            float4 v = *(float4*)&wreg[rl * 64 + l15 * 4];
            int gm = m0 + wm * 64 + ci * 32 + rl;
            v.x += bias4.x; v.y += bias4.y; v.z += bias4.z; v.w += bias4.w;
            if (do_gelu) { v.x = gelu_f(v.x); v.y = gelu_f(v.y); v.z = gelu_f(v.z); v.w = gelu_f(v.w); }
            v.x = v.x * scl4.x + shf4.x; v.y = v.y * scl4.y + shf4.y;
            v.z = v.z * scl4.z + shf4.z; v.w = v.w * scl4.w + shf4.w;
            size_t crow = (size_t)gm;
            if (rc_mod > 0) crow = (size_t)(gm / rc_mod) * 449 + (gm % rc_mod);
            if (R) {
                float4 r4 = *(const float4*)&R[crow * N + gn0];
                v.x += r4.x; v.y += r4.y; v.z += r4.z; v.w += r4.w;
            }
            if (pe_mode) {
                int bi = gm / TFRONT, t = gm - bi * TFRONT;
                float ft = (float)t;
                float f0 = __expf(-9.210340371976184f * (float)gn0 * (1.f / 256.f));
                float f1 = __expf(-9.210340371976184f * (float)(gn0 + 2) * (1.f / 256.f));
                float a0 = ft * f0, a1 = ft * f1;
                v.x += __sinf(a0); v.y += __cosf(a0);
                v.z += __sinf(a1); v.w += __cosf(a1);
                *(float4*)&((float*)C)[(size_t)(bi * 449 + 1 + t) * 256 + gn0] = v;
            } else if (out_mode == 1) {
                uint2 pk = make_uint2(pack2bf(v.x, v.y), pack2bf(v.z, v.w));
                *(uint2*)&((ushort_t*)C)[crow * N + gn0] = pk;
            } else {
                *(float4*)&((float*)C)[crow * N + gn0] = v;
                if (out_mode == 2) {
                    int bi = gm / TFRONT, t = gm - bi * TFRONT;
                    size_t grow = (size_t)(bi * GROWS + 8 + t);
                    uint2 pk = make_uint2(pack2bf(v.x, v.y), pack2bf(v.z, v.w));
                    *(uint2*)&C2[grow * N + gn0] = pk;
                }
            }
        }
    }
}

// ---- prep: transposes + conv repack + BN + guards + cls copy ------
__global__ __launch_bounds__(256) void prep_all(
    const float* __restrict__ ipw,  const float* __restrict__ mpw,
    const float* __restrict__ qkvw, const float* __restrict__ outw,
    const float* __restrict__ fw1,  const float* __restrict__ fw2,
    const float* __restrict__ cw1,
    ushort_t* ipwT, ushort_t* mpwT, ushort_t* qkvT, ushort_t* outwT,
    ushort_t* fw1T, ushort_t* fw2T, ushort_t* cw1T,
    const float* __restrict__ convw, ushort_t* wrepT,
    const float* __restrict__ bg, const float* __restrict__ bb,
    const float* __restrict__ rm, const float* __restrict__ rv,
    float* bnsc, float* bnsh,
    ushort_t* h448g, const float* __restrict__ clstok, float* h449)
{
    const int bid = blockIdx.x;
    if (bid >= 3175) {                        // cls-token copy into h449 row 0
        int b = bid - 3175;
        h449[(size_t)b * TTT * 256 + threadIdx.x] = clstok[threadIdx.x];
        return;
    }
    if (bid >= 3111) {                        // zero guard rows of h448g
        int b = bid - 3111;
        #pragma unroll
        for (int j = 0; j < 8; ++j)
            h448g[(size_t)(b * GROWS + j) * 256 + threadIdx.x] = 0;
        return;
    }
    if (bid >= 3108) {                        // BN folding
        int i = (bid - 3108) * 256 + threadIdx.x;
        if (i < 768) {
            float sc = rsqrtf(rv[i] + 1e-5f) * bg[i];
            bnsc[i] = sc;
            bnsh[i] = bb[i] - rm[i] * sc;
        }
        return;
    }
    if (bid >= 804) {                         // conv weight repack
        int i = (bid - 804) * 256 + threadIdx.x;
        int s = i / 196608; int o = i - s * 196608;
        int ci = o & 255; int t3 = (o >> 8) % 3; int co = o / 768;
        wrepT[i] = f2bf(convw[(((size_t)s * 256 + co) * 256 + ci) * 3 + t3]);
        return;
    }
    const float* src; ushort_t* dst; int K, N, local;
    if (bid < 4)        { src = ipw;  dst = ipwT;  K = 64;   N = 256;  local = bid; }
    else if (bid < 20)  { src = mpw;  dst = mpwT;  K = 256;  N = 256;  local = bid - 4; }
    else if (bid < 212) { int l = bid - 20;  int z = l / 48; l -= z * 48;
                          src = qkvw + (size_t)z * 196608; dst = qkvT + (size_t)z * 196608;
                          K = 256;  N = 768;  local = l; }
    else if (bid < 276) { int l = bid - 212; int z = l / 16; l -= z * 16;
                          src = outw + (size_t)z * 65536;  dst = outwT + (size_t)z * 65536;
                          K = 256;  N = 256;  local = l; }
    else if (bid < 532) { int l = bid - 276; int z = l / 64; l -= z * 64;
                          src = fw1 + (size_t)z * 262144;  dst = fw1T + (size_t)z * 262144;
                          K = 256;  N = 1024; local = l; }
    else if (bid < 788) { int l = bid - 532; int z = l / 64; l -= z * 64;
                          src = fw2 + (size_t)z * 262144;  dst = fw2T + (size_t)z * 262144;
                          K = 1024; N = 256;  local = l; }
    else                { src = cw1;  dst = cw1T;  K = 256;  N = 256;  local = bid - 788; }

    __shared__ float tile[64][65];
    int nt = N / 64;
    int n0 = (local % nt) * 64, k0 = (local / nt) * 64;
    int tx = threadIdx.x & 63, ty = threadIdx.x >> 6;
    #pragma unroll
    for (int i = 0; i < 16; ++i)
        tile[i * 4 + ty][tx] = src[(size_t)(k0 + i * 4 + ty) * N + n0 + tx];
    __syncthreads();
    #pragma unroll
    for (int i = 0; i < 16; ++i) {
        int n = i * 4 + ty;
        dst[(size_t)(n0 + n) * K + k0 + tx] = f2bf(tile[tx][n]);
    }
}

// ---------------- gate softmax + fuse, wave-per-row ----------------
__global__ __launch_bounds__(256) void gate_fuse(
    const ushort_t* __restrict__ conv,  // [3][Mrows][256]
    const float* __restrict__ gw, const float* __restrict__ gb,
    ushort_t* __restrict__ fused, int Mrows)
{
    const int w = threadIdx.x >> 6, lane = threadIdx.x & 63;
    const int m = blockIdx.x * 4 + w;
    const int d0 = lane * 4;
    float vals[3][4];
    float p0 = 0.f, p1 = 0.f, p2 = 0.f;
    #pragma unroll
    for (int s = 0; s < 3; ++s) {
        uint2 pk = *(const uint2*)&conv[((size_t)s * Mrows + m) * 256 + d0];
        vals[s][0] = bf2f(pk.x & 0xffff); vals[s][1] = bf2f(pk.x >> 16);
        vals[s][2] = bf2f(pk.y & 0xffff); vals[s][3] = bf2f(pk.y >> 16);
        #pragma unroll
        for (int e = 0; e < 4; ++e) {
            const float* wp = gw + (size_t)(s * 256 + d0 + e) * 3;
            float v = vals[s][e];
            p0 += v * wp[0]; p1 += v * wp[1]; p2 += v * wp[2];
        }
    }
    #pragma unroll
    for (int o = 32; o > 0; o >>= 1) {
        p0 += __shfl_xor(p0, o); p1 += __shfl_xor(p1, o); p2 += __shfl_xor(p2, o);
    }
    float l0 = p0 + gb[0], l1 = p1 + gb[1], l2 = p2 + gb[2];
    float mx = fmaxf(l0, fmaxf(l1, l2));
    float e0 = __expf(l0 - mx), e1 = __expf(l1 - mx), e2 = __expf(l2 - mx);
    float inv = 1.f / (e0 + e1 + e2);
    float g0 = e0 * inv, g1 = e1 * inv, g2 = e2 * inv;
    unsigned r0 = pack2bf(vals[0][0] * g0 + vals[1][0] * g1 + vals[2][0] * g2,
                          vals[0][1] * g0 + vals[1][1] * g1 + vals[2][1] * g2);
    unsigned r1 = pack2bf(vals[0][2] * g0 + vals[1][2] * g1 + vals[2][2] * g2,
                          vals[0][3] * g0 + vals[1][3] * g1 + vals[2][3] * g2);
    *(uint2*)&fused[(size_t)m * 256 + d0] = make_uint2(r0, r1);
}

// ---------------- layernorm, 2 rows/wave; X = h449 via row-map ---------------
__global__ __launch_bounds__(256) void ln_rows8(
    const float* __restrict__ X, ushort_t* __restrict__ Y,
    const float* __restrict__ g, const float* __restrict__ b,
    int xmod, int nrows)
{
    const int w = threadIdx.x >> 6, lane = threadIdx.x & 63;
    const int row0 = blockIdx.x * 8 + w * 2;
    if (row0 >= nrows) return;
    const int d0 = lane * 4;
    const bool two = (row0 + 1) < nrows;
    size_t xr0 = (size_t)(row0 / xmod) * 449 + (row0 % xmod);
    int row1 = row0 + 1;
    size_t xr1 = two ? (size_t)(row1 / xmod) * 449 + (row1 % xmod) : xr0;
    float4 va = *(const float4*)&X[xr0 * 256 + d0];
    float4 vb = *(const float4*)&X[xr1 * 256 + d0];
    float sa = va.x + va.y + va.z + va.w;
    float sb = vb.x + vb.y + vb.z + vb.w;
    #pragma unroll
    for (int o = 32; o > 0; o >>= 1) { sa += __shfl_xor(sa, o); sb += __shfl_xor(sb, o); }
    float ma = sa * (1.f / 256.f), mb = sb * (1.f / 256.f);
    float ax = va.x - ma, ay = va.y - ma, az = va.z - ma, aw = va.w - ma;
    float bx = vb.x - mb, by = vb.y - mb, bz = vb.z - mb, bw = vb.w - mb;
    float s2a = ax * ax + ay * ay + az * az + aw * aw;
    float s2b = bx * bx + by * by + bz * bz + bw * bw;
    #pragma unroll
    for (int o = 32; o > 0; o >>= 1) { s2a += __shfl_xor(s2a, o); s2b += __shfl_xor(s2b, o); }
    float ia = rsqrtf(s2a * (1.f / 256.f) + 1e-5f);
    float ib = rsqrtf(s2b * (1.f / 256.f) + 1e-5f);
    float4 gv = *(const float4*)&g[d0];
    float4 bv = *(const float4*)&b[d0];
    *(uint2*)&Y[(size_t)row0 * 256 + d0] = make_uint2(
        pack2bf(ax * ia * gv.x + bv.x, ay * ia * gv.y + bv.y),
        pack2bf(az * ia * gv.z + bv.z, aw * ia * gv.w + bv.w));
    if (two)
        *(uint2*)&Y[(size_t)row1 * 256 + d0] = make_uint2(
            pack2bf(bx * ib * gv.x + bv.x, by * ib * gv.y + bv.y),
            pack2bf(bz * ib * gv.z + bv.z, bw * ib * gv.w + bv.w));
}

// ---------------- attention v8b: compact strides, window [qb-32, qb+47] ------
#define KP    480
#define KPAD  36
#define VPAD  488
#define PTPAD 40
__global__ __launch_bounds__(256, 2) void attn8_kernel(
    const ushort_t* __restrict__ qkv,
    const float* __restrict__ alpha,
    ushort_t* __restrict__ O,
    int kst, int nqt, int ost)
{
    __shared__ ushort_t sK[KP][KPAD];
    __shared__ ushort_t sVt[32][VPAD];
    __shared__ ushort_t sPT[4][16][PTPAD];
    __shared__ float sRed[4];

    const int bh = blockIdx.x;
    const int b = bh >> 3, h = bh & 7;
    const int tid = threadIdx.x;
    const int w = tid >> 6, lane = tid & 63;
    const int l15 = lane & 15, quad = lane >> 4;
    const float LOG2E = 1.4426950408889634f;
    const float scale2 = 0.17677669529663687f * LOG2E;

    float av = alpha[h];
    float a_sp = (av > 20.f) ? av : log1pf(__expf(av));
    const float a_h = a_sp * LOG2E;

    {
        int r0 = tid >> 2, c = (tid & 3) * 8;
        float knmax = 0.f;
        for (int r = r0; r < kst; r += 64) {
            const ushort_t* src = qkv + ((size_t)(b * kst + r)) * 768 + 256 + h * 32 + c;
            short8 kv = *(const short8*)src;
            short8 vv = *(const short8*)(src + 256);
            *(short8*)&sK[r][c] = kv;
            float ssq = 0.f;
            #pragma unroll
            for (int j = 0; j < 8; ++j) {
                float kf = bf2f(((const ushort_t*)&kv)[j]);
                ssq += kf * kf;
                sVt[c + j][r] = ((const ushort_t*)&vv)[j];
            }
            ssq += __shfl_xor(ssq, 1);
            ssq += __shfl_xor(ssq, 2);
            knmax = fmaxf(knmax, ssq);
        }
        #pragma unroll
        for (int o = 32; o > 0; o >>= 1) knmax = fmaxf(knmax, __shfl_xor(knmax, o));
        if (lane == 0) sRed[w] = knmax;
    }
    __syncthreads();
    const float kmax2 = fmaxf(fmaxf(sRed[0], sRed[1]), fmaxf(sRed[2], sRed[3]));

    for (int qt = w; qt < nqt; qt += 4) {
        const int qb = qt * 16;
        const int qrow = qb + l15;
        short8 qfrag = *(const short8*)(qkv + ((size_t)(b * kst + qrow)) * 768 + h * 32 + quad * 8);
        const f32x4 z = {0.f, 0.f, 0.f, 0.f};

        float qn = 0.f;
        #pragma unroll
        for (int j = 0; j < 8; ++j) { float f = bf2f(qfrag[j]); qn += f * f; }
        qn += __shfl_xor(qn, 16);
        qn += __shfl_xor(qn, 32);
        const float Mr = scale2 * sqrtf(qn * kmax2);
        const float fq = (float)qrow;

        int ch_lo = (qb - 32) >> 5; if (ch_lo < 0) ch_lo = 0;
        int ch_hi = (qb + 47) >> 5;
        const int ch_max = (kst >> 5) - 1;
        if (ch_hi > ch_max) ch_hi = ch_max;

        f32x4 o0 = z, o1 = z;
        float lsum = 0.f;
        for (int ch = ch_lo; ch <= ch_hi; ++ch) {
            const int kb = ch * 32;
            short8 kf0 = *(const short8*)&sK[kb + l15][quad * 8];
            short8 kf1 = *(const short8*)&sK[kb + 16 + l15][quad * 8];
            f32x4 s0 = __builtin_amdgcn_mfma_f32_16x16x32_bf16(kf0, qfrag, z, 0, 0, 0);
            f32x4 s1 = __builtin_amdgcn_mfma_f32_16x16x32_bf16(kf1, qfrag, z, 0, 0, 0);
            float p0[4], p1[4];
            #pragma unroll
            for (int r = 0; r < 4; ++r) {
                int k0 = kb + quad * 4 + r;
                int k1 = k0 + 16;
                float b0 = s0[r] * scale2 - (a_h * fabsf(fq - (float)k0) + Mr);
                float b1 = s1[r] * scale2 - (a_h * fabsf(fq - (float)k1) + Mr);
                p0[r] = exp2f(b0);
                p1[r] = exp2f(b1);
            }
            lsum += (p0[0] + p0[1]) + (p0[2] + p0[3]) + (p1[0] + p1[1]) + (p1[2] + p1[3]);
            unsigned* prow = (unsigned*)&sPT[w][l15][0];
            prow[quad * 2]     = pack2bf(p0[0], p0[1]);
            prow[quad * 2 + 1] = pack2bf(p0[2], p0[3]);
            prow[8 + quad * 2]     = pack2bf(p1[0], p1[1]);
            prow[8 + quad * 2 + 1] = pack2bf(p1[2], p1[3]);
            short8 pB = *(const short8*)&sPT[w][l15][quad * 8];
            short8 v0 = *(const short8*)&sVt[l15][kb + quad * 8];
            short8 v1 = *(const short8*)&sVt[16 + l15][kb + quad * 8];
            o0 = __builtin_amdgcn_mfma_f32_16x16x32_bf16(v0, pB, o0, 0, 0, 0);
            o1 = __builtin_amdgcn_mfma_f32_16x16x32_bf16(v1, pB, o1, 0, 0, 0);
        }
        lsum += __shfl_xor(lsum, 16);
        lsum += __shfl_xor(lsum, 32);

        {
            float inv = 1.f / lsum;
            unsigned* dst = (unsigned*)&O[((size_t)(b * ost + qrow)) * 256 + h * 32 + quad * 4];
            dst[0] = pack2bf(o0[0] * inv, o0[1] * inv);
            dst[1] = pack2bf(o0[2] * inv, o0[3] * inv);
            dst[8] = pack2bf(o1[0] * inv, o1[1] * inv);
            dst[9] = pack2bf(o1[2] * inv, o1[3] * inv);
        }
    }
}

// ---------------- fused head: final LN + cls MLP + logit (1 block/batch) -----
__global__ __launch_bounds__(256) void head_kernel(
    const float* __restrict__ h449,
    const float* __restrict__ fing, const float* __restrict__ finb,
    const ushort_t* __restrict__ cw1T, const float* __restrict__ cb1,
    const float* __restrict__ cw2, const float* __restrict__ b2,
    float* __restrict__ out)
{
    __shared__ float xn[256];
    __shared__ float red[4];
    const int b = blockIdx.x, d = threadIdx.x;
    float v = h449[(size_t)b * TTT * 256 + d];
    float s = v;
    #pragma unroll
    for (int o = 32; o > 0; o >>= 1) s += __shfl_down(s, o, 64);
    if ((d & 63) == 0) red[d >> 6] = s;
    __syncthreads();
    float mean = (red[0] + red[1] + red[2] + red[3]) * (1.f / 256.f);
    __syncthreads();
    float diff = v - mean;
    float s2 = diff * diff;
    #pragma unroll
    for (int o = 32; o > 0; o >>= 1) s2 += __shfl_down(s2, o, 64);
    if ((d & 63) == 0) red[d >> 6] = s2;
    __syncthreads();
    float rstd = rsqrtf((red[0] + red[1] + red[2] + red[3]) * (1.f / 256.f) + 1e-5f);
    xn[d] = diff * rstd * fing[d] + finb[d];
    __syncthreads();
    const ushort_t* wrow = cw1T + (size_t)d * 256;
    float acc = 0.f;
    #pragma unroll 4
    for (int k = 0; k < 256; k += 8) {
        short8 wv = *(const short8*)&wrow[k];
        #pragma unroll
        for (int j = 0; j < 8; ++j) acc += xn[k + j] * bf2f(((const ushort_t*)&wv)[j]);
    }
    float p = gelu_f(acc + cb1[d]) * cw2[d];
    #pragma unroll
    for (int o = 32; o > 0; o >>= 1) p += __shfl_down(p, o, 64);
    __syncthreads();
    if ((d & 63) == 0) red[d >> 6] = p;
    __syncthreads();
    if (d == 0) out[b] = red[0] + red[1] + red[2] + red[3] + b2[0];
}

// ---------------- orchestration ----------------
extern "C" void kernel_launch(void* const* d_in, const int* in_sizes, int n_in,
                              void* d_out, int out_size, void* d_ws, size_t ws_size,
                              hipStream_t stream)
{
    const float* x      = (const float*)d_in[0];
    const float* ipw    = (const float*)d_in[1];
    const float* ipb    = (const float*)d_in[2];
    const float* convw  = (const float*)d_in[3];
    const float* convb  = (const float*)d_in[4];
    const float* bng    = (const float*)d_in[5];
    const float* bnb    = (const float*)d_in[6];
    const float* bnrm   = (const float*)d_in[7];
    const float* bnrv   = (const float*)d_in[8];
    const float* gatew  = (const float*)d_in[9];
    const float* gateb  = (const float*)d_in[10];
    const float* mpw    = (const float*)d_in[11];
    const float* mpb    = (const float*)d_in[12];
    const float* clstok = (const float*)d_in[13];
    const float* qkvw   = (const float*)d_in[14];
    const float* qkvb   = (const float*)d_in[15];
    const float* outw   = (const float*)d_in[16];
    const float* outb   = (const float*)d_in[17];
    const float* alpha  = (const float*)d_in[18];
    const float* ln1g   = (const float*)d_in[19];
    const float* ln1b   = (const float*)d_in[20];
    const float* ln2g   = (const float*)d_in[21];
    const float* ln2b   = (const float*)d_in[22];
    const float* fw1    = (const float*)d_in[23];
    const float* fb1    = (const float*)d_in[24];
    const float* fw2    = (const float*)d_in[25];
    const float* fb2    = (const float*)d_in[26];
    const float* fing   = (const float*)d_in[27];
    const float* finb   = (const float*)d_in[28];
    const float* cw1    = (const float*)d_in[29];
    const float* cb1    = (const float*)d_in[30];
    const float* cw2    = (const float*)d_in[31];
    const float* cb2    = (const float*)d_in[32];

    const int KL[4] = {160, 128, 96, 64};
    const int QL[4] = {128, 96, 64, 16};

    // ---- workspace layout ----
    char* base = (char*)d_ws;
    size_t off = 0;
    auto alloc = [&](size_t bytes) { char* p = base + off; off += (bytes + 255) & ~(size_t)255; return p; };
    float*    h448  = (float*)alloc((size_t)MFRONT * 256 * 4);
    float*    h449  = (float*)alloc((size_t)MPAD * 256 * 4);
    float*    bufA  = (float*)alloc((size_t)MFRONT * 768 * 4);
    ushort_t* conv_bf = (ushort_t*)bufA;
    ushort_t* qkv_bf  = (ushort_t*)bufA;
    ushort_t* bufMid  = (ushort_t*)bufA;
    ushort_t* bufB  = (ushort_t*)alloc((size_t)MFRONT * 256 * 2);
    ushort_t* bufB2 = (ushort_t*)alloc((size_t)MFRONT * 256 * 2);
    ushort_t* bufC  = (ushort_t*)alloc((size_t)64 * 128 * 256 * 2);
    ushort_t* h448g = (ushort_t*)alloc((size_t)BB * GROWS * 256 * 2);
    ushort_t* wrepT = (ushort_t*)alloc((size_t)3 * 256 * 768 * 2);
    ushort_t* ipwT  = (ushort_t*)alloc((size_t)64 * 256 * 2);
    ushort_t* mpwT  = (ushort_t*)alloc((size_t)256 * 256 * 2);
    ushort_t* qkvT  = (ushort_t*)alloc((size_t)4 * 768 * 256 * 2);
    ushort_t* outwT = (ushort_t*)alloc((size_t)4 * 256 * 256 * 2);
    ushort_t* fw1T  = (ushort_t*)alloc((size_t)4 * 1024 * 256 * 2);
    ushort_t* fw2T  = (ushort_t*)alloc((size_t)4 * 256 * 1024 * 2);
    ushort_t* cw1T  = (ushort_t*)alloc((size_t)256 * 256 * 2);
    float*    bnsc  = (float*)alloc(768 * 4);
    float*    bnsh  = (float*)alloc(768 * 4);

    auto gemm = [&](const ushort_t* A, const ushort_t* Bt, void* C, ushort_t* C2,
                    const float* bias, const float* scl, const float* shf, const float* R,
                    int M, int N, int K, int a_dil, int gelu_fl, int omode, int pemode,
                    int rc_mod = 0, int gz = 1) {
        dim3 grid(N / 128, M / 128, gz);
        hipLaunchKernelGGL(gemm_bf16, grid, dim3(256), 0, stream,
                           A, Bt, C, C2, bias, scl, shf, R, M, N, K, a_dil, gelu_fl,
                           omode, pemode, rc_mod);
    };

    // ---- prep: transposes + conv repack + BN + guard zero + cls copy ----
    hipLaunchKernelGGL(prep_all, dim3(3239), dim3(256), 0, stream,
                       ipw, mpw, qkvw, outw, fw1, fw2, cw1,
                       ipwT, mpwT, qkvT, outwT, fw1T, fw2T, cw1T,
                       convw, wrepT, bng, bnb, bnrm, bnrv, bnsc, bnsh,
                       h448g, clstok, h449);

    // ---- input projection on rows t<160: h448 f32 + h448g bf16 (guarded) ----
    gemm((const ushort_t*)x, ipwT, h448, h448g, ipb, nullptr, nullptr, nullptr,
         MFRONT, 256, 64, -2, 0, 2, 0);

    // ---- conv (3 scales in z), DMA staging from h448g, fused gelu+BN ----
    gemm(h448g, wrepT, conv_bf, nullptr, convb, bnsc, bnsh, nullptr,
         MFRONT, 256, 768, -1, 1, 1, 0, 0, 3);
    hipLaunchKernelGGL(gate_fuse, dim3(MFRONT / 4), dim3(256), 0, stream,
                       conv_bf, gatew, gateb, bufB, MFRONT);
    // ms_proj + residual + PE -> h449 rows 1..160 per batch
    gemm(bufB, mpwT, h449, nullptr, mpb, nullptr, nullptr, h448,
         MFRONT, 256, 256, 0, 0, 0, 1);

    // ---- transformer layers on the shrinking cone ----
    for (int l = 0; l < LAYERS; ++l) {
        const int Kl = KL[l], Ql = QL[l];
        const int MK = 64 * Kl, MQ = 64 * Ql;
        hipLaunchKernelGGL(ln_rows8, dim3((MK + 7) / 8), dim3(256), 0, stream,
                           h449, bufB2, ln1g + l * 256, ln1b + l * 256, Kl, MK);
        gemm(bufB2, qkvT + (size_t)l * 768 * 256, qkv_bf, nullptr, qkvb + l * 768,
             nullptr, nullptr, nullptr, MK, 768, 256, 0, 0, 1, 0);
        hipLaunchKernelGGL(attn8_kernel, dim3(BB * HEADS), dim3(256), 0, stream,
                           qkv_bf, alpha + l * HEADS, bufC, Kl, Ql / 16, Ql);
        gemm(bufC, outwT + (size_t)l * 65536, h449, nullptr, outb + l * 256,
             nullptr, nullptr, h449, MQ, 256, 256, 0, 0, 0, 0, Ql);
        hipLaunchKernelGGL(ln_rows8, dim3((MQ + 7) / 8), dim3(256), 0, stream,
                           h449, bufB2, ln2g + l * 256, ln2b + l * 256, Ql, MQ);
        gemm(bufB2, fw1T + (size_t)l * 262144, bufMid, nullptr, fb1 + l * 1024,
             nullptr, nullptr, nullptr, MQ, 1024, 256, 0, 1, 1, 0);
        gemm(bufMid, fw2T + (size_t)l * 262144, h449, nullptr, fb2 + l * 256,
             nullptr, nullptr, h449, MQ, 256, 1024, 0, 0, 0, 0, Ql);
    }

    // ---- fused head: final LN + cls MLP + logit ----
    hipLaunchKernelGGL(head_kernel, dim3(BB), dim3(256), 0, stream,
                       h449, fing, finb, cw1T, cb1, cw2, cb2, (float*)d_out);
}